// Round 1
// baseline (173.565 us; speedup 1.0000x reference)
//
#include <hip/hip_runtime.h>
#include <math.h>

#define DIM    128
#define DIM2   256
#define NSIGN  4
#define CCONST 0.618f
#define TB     8
#define NTHR   256

// Build W1T[j][k] = W1[k][j]  (W1 is [256][128])
//       W2T[k][i] = W2[i][k]  (W2 is [128][256])
__global__ void prep_transpose(const float* __restrict__ W1,
                               const float* __restrict__ W2,
                               float* __restrict__ W1T,
                               float* __restrict__ W2T) {
    int idx = blockIdx.x * blockDim.x + threadIdx.x;
    if (idx >= DIM * DIM2) return;
    int k = idx >> 7;            // W1 row (0..255)
    int j = idx & (DIM - 1);     // W1 col (0..127)
    W1T[j * DIM2 + k] = W1[idx];
    int i  = idx >> 8;           // W2 row (0..127)
    int kk = idx & (DIM2 - 1);   // W2 col (0..255)
    W2T[kk * DIM + i] = W2[idx];
}

__global__ __launch_bounds__(NTHR, 2)
void fused_connection(const float* __restrict__ input_,
                      const float* __restrict__ W1,
                      const float* __restrict__ b1,
                      const float* __restrict__ W2,
                      const float* __restrict__ b2,
                      const float* __restrict__ W1T,
                      const float* __restrict__ W2T,
                      float* __restrict__ out) {
    // Per-block LDS: 36 KB total
    __shared__ __align__(16) float xv[TB][DIM2]; // x | v ; x-half becomes vc after stage 2
    __shared__ __align__(16) float am[TB][DIM2]; // a = relu(h); mask = (a > 0)
    __shared__ __align__(16) float wb[TB][DIM2]; // w = v@W1^T; masked in stage 3
    __shared__ __align__(16) float ub[TB][DIM2]; // mu = mask * u
    __shared__ __align__(16) float sb[TB][DIM];  // s = sigmoid(z)

    const int t  = threadIdx.x;
    const int b0 = blockIdx.x * TB;

    // ---------- Phase 0: load x|v rows (TB*256 floats, coalesced float4) ----------
    {
        const float4* src = (const float4*)(input_ + (size_t)b0 * DIM2);
        float4* dst = (float4*)(&xv[0][0]);
        dst[t]        = src[t];
        dst[t + NTHR] = src[t + NTHR];
    }
    __syncthreads();

    // copy v -> out[:, :128]
    {
        int row  = t >> 5;
        int col4 = (t & 31) * 4;
        float4 vv = *(const float4*)(&xv[row][DIM + col4]);
        *(float4*)(out + (size_t)(b0 + row) * DIM2 + col4) = vv;
    }

    // ---------- Stage 1: h[b,k] = x.W1[k,:] + b1[k] ; w[b,k] = v.W1[k,:] ----------
    // thread tile: 2 rows x 4 cols, N=256, K=128
    {
        const int rg = t >> 6, cg = t & 63;
        const int r0 = rg * 2, c0 = cg * 4;
        float ha[2][4], wa[2][4];
        #pragma unroll
        for (int cc = 0; cc < 4; ++cc) {
            float bv = b1[c0 + cc];
            ha[0][cc] = bv;  ha[1][cc] = bv;
            wa[0][cc] = 0.f; wa[1][cc] = 0.f;
        }
        #pragma unroll 2
        for (int j4 = 0; j4 < DIM; j4 += 4) {
            float4 wv[4];
            #pragma unroll
            for (int cc = 0; cc < 4; ++cc)
                wv[cc] = *(const float4*)(W1 + (size_t)(c0 + cc) * DIM + j4);
            float4 xr[2], vr[2];
            #pragma unroll
            for (int rr = 0; rr < 2; ++rr) {
                xr[rr] = *(const float4*)(&xv[r0 + rr][j4]);
                vr[rr] = *(const float4*)(&xv[r0 + rr][DIM + j4]);
            }
            #pragma unroll
            for (int rr = 0; rr < 2; ++rr)
                #pragma unroll
                for (int cc = 0; cc < 4; ++cc) {
                    ha[rr][cc] = fmaf(xr[rr].x, wv[cc].x, ha[rr][cc]);
                    ha[rr][cc] = fmaf(xr[rr].y, wv[cc].y, ha[rr][cc]);
                    ha[rr][cc] = fmaf(xr[rr].z, wv[cc].z, ha[rr][cc]);
                    ha[rr][cc] = fmaf(xr[rr].w, wv[cc].w, ha[rr][cc]);
                    wa[rr][cc] = fmaf(vr[rr].x, wv[cc].x, wa[rr][cc]);
                    wa[rr][cc] = fmaf(vr[rr].y, wv[cc].y, wa[rr][cc]);
                    wa[rr][cc] = fmaf(vr[rr].z, wv[cc].z, wa[rr][cc]);
                    wa[rr][cc] = fmaf(vr[rr].w, wv[cc].w, wa[rr][cc]);
                }
        }
        #pragma unroll
        for (int rr = 0; rr < 2; ++rr) {
            float4 av, wv4;
            av.x = fmaxf(ha[rr][0], 0.f); av.y = fmaxf(ha[rr][1], 0.f);
            av.z = fmaxf(ha[rr][2], 0.f); av.w = fmaxf(ha[rr][3], 0.f);
            wv4.x = wa[rr][0]; wv4.y = wa[rr][1]; wv4.z = wa[rr][2]; wv4.w = wa[rr][3];
            *(float4*)(&am[r0 + rr][c0]) = av;
            *(float4*)(&wb[r0 + rr][c0]) = wv4;
        }
    }
    __syncthreads();

    // ---------- Stage 2: z[b,i] = a.W2[i,:] + b2[i]; s, c, vc = v^2*c ----------
    // thread tile: 2 rows x 2 cols, N=128, K=256
    {
        const int rg = t >> 6, cg = t & 63;
        const int r0 = rg * 2, c0 = cg * 2;
        float za[2][2];
        #pragma unroll
        for (int cc = 0; cc < 2; ++cc) {
            float bv = b2[c0 + cc];
            za[0][cc] = bv; za[1][cc] = bv;
        }
        #pragma unroll 2
        for (int k4 = 0; k4 < DIM2; k4 += 4) {
            float4 wv[2];
            #pragma unroll
            for (int cc = 0; cc < 2; ++cc)
                wv[cc] = *(const float4*)(W2 + (size_t)(c0 + cc) * DIM2 + k4);
            float4 ar[2];
            #pragma unroll
            for (int rr = 0; rr < 2; ++rr)
                ar[rr] = *(const float4*)(&am[r0 + rr][k4]);
            #pragma unroll
            for (int rr = 0; rr < 2; ++rr)
                #pragma unroll
                for (int cc = 0; cc < 2; ++cc) {
                    za[rr][cc] = fmaf(ar[rr].x, wv[cc].x, za[rr][cc]);
                    za[rr][cc] = fmaf(ar[rr].y, wv[cc].y, za[rr][cc]);
                    za[rr][cc] = fmaf(ar[rr].z, wv[cc].z, za[rr][cc]);
                    za[rr][cc] = fmaf(ar[rr].w, wv[cc].w, za[rr][cc]);
                }
        }
        #pragma unroll
        for (int rr = 0; rr < 2; ++rr)
            #pragma unroll
            for (int cc = 0; cc < 2; ++cc) {
                int row = r0 + rr, i = c0 + cc;
                float s  = 1.f / (1.f + __expf(-za[rr][cc]));
                sb[row][i] = s;
                float sg = (i < NSIGN) ? -1.f : 1.f;
                float cv = sg * s * (1.f - s);
                float vvl = xv[row][DIM + i];
                xv[row][i] = vvl * vvl * cv;   // vc overwrites dead x-half
            }
    }
    __syncthreads();

    // ---------- Stage 3: u[b,k] = vc.W2T[k,:]; then mu = m*u, mw = m*w ----------
    // thread tile: 2 rows x 4 cols, N=256, K=128
    {
        const int rg = t >> 6, cg = t & 63;
        const int r0 = rg * 2, c0 = cg * 4;
        float ua[2][4] = {{0.f,0.f,0.f,0.f},{0.f,0.f,0.f,0.f}};
        #pragma unroll 2
        for (int i4 = 0; i4 < DIM; i4 += 4) {
            float4 wv[4];
            #pragma unroll
            for (int cc = 0; cc < 4; ++cc)
                wv[cc] = *(const float4*)(W2T + (size_t)(c0 + cc) * DIM + i4);
            float4 vcr[2];
            #pragma unroll
            for (int rr = 0; rr < 2; ++rr)
                vcr[rr] = *(const float4*)(&xv[r0 + rr][i4]);
            #pragma unroll
            for (int rr = 0; rr < 2; ++rr)
                #pragma unroll
                for (int cc = 0; cc < 4; ++cc) {
                    ua[rr][cc] = fmaf(vcr[rr].x, wv[cc].x, ua[rr][cc]);
                    ua[rr][cc] = fmaf(vcr[rr].y, wv[cc].y, ua[rr][cc]);
                    ua[rr][cc] = fmaf(vcr[rr].z, wv[cc].z, ua[rr][cc]);
                    ua[rr][cc] = fmaf(vcr[rr].w, wv[cc].w, ua[rr][cc]);
                }
        }
        #pragma unroll
        for (int rr = 0; rr < 2; ++rr) {
            int row = r0 + rr;
            float4 amv = *(const float4*)(&am[row][c0]);
            float4 wv4 = *(const float4*)(&wb[row][c0]);
            float4 uo, wo;
            uo.x = (amv.x > 0.f) ? ua[rr][0] : 0.f;  wo.x = (amv.x > 0.f) ? wv4.x : 0.f;
            uo.y = (amv.y > 0.f) ? ua[rr][1] : 0.f;  wo.y = (amv.y > 0.f) ? wv4.y : 0.f;
            uo.z = (amv.z > 0.f) ? ua[rr][2] : 0.f;  wo.z = (amv.z > 0.f) ? wv4.z : 0.f;
            uo.w = (amv.w > 0.f) ? ua[rr][3] : 0.f;  wo.w = (amv.w > 0.f) ? wv4.w : 0.f;
            *(float4*)(&ub[row][c0]) = uo;
            *(float4*)(&wb[row][c0]) = wo;
        }
    }
    __syncthreads();

    // ---------- Stage 4: t1[b,j] = mu.W1T[j,:]; t2[b,j] = mw.W2[j,:]; dv ----------
    // thread tile: 2 rows x 2 cols, N=128, K=256
    {
        const int rg = t >> 6, cg = t & 63;
        const int r0 = rg * 2, c0 = cg * 2;
        float t1a[2][2] = {{0.f,0.f},{0.f,0.f}};
        float t2a[2][2] = {{0.f,0.f},{0.f,0.f}};
        #pragma unroll 2
        for (int k4 = 0; k4 < DIM2; k4 += 4) {
            float4 w1v[2], w2v[2];
            #pragma unroll
            for (int cc = 0; cc < 2; ++cc) {
                w1v[cc] = *(const float4*)(W1T + (size_t)(c0 + cc) * DIM2 + k4);
                w2v[cc] = *(const float4*)(W2  + (size_t)(c0 + cc) * DIM2 + k4);
            }
            float4 ur[2], wr[2];
            #pragma unroll
            for (int rr = 0; rr < 2; ++rr) {
                ur[rr] = *(const float4*)(&ub[r0 + rr][k4]);
                wr[rr] = *(const float4*)(&wb[r0 + rr][k4]);
            }
            #pragma unroll
            for (int rr = 0; rr < 2; ++rr)
                #pragma unroll
                for (int cc = 0; cc < 2; ++cc) {
                    t1a[rr][cc] = fmaf(ur[rr].x, w1v[cc].x, t1a[rr][cc]);
                    t1a[rr][cc] = fmaf(ur[rr].y, w1v[cc].y, t1a[rr][cc]);
                    t1a[rr][cc] = fmaf(ur[rr].z, w1v[cc].z, t1a[rr][cc]);
                    t1a[rr][cc] = fmaf(ur[rr].w, w1v[cc].w, t1a[rr][cc]);
                    t2a[rr][cc] = fmaf(wr[rr].x, w2v[cc].x, t2a[rr][cc]);
                    t2a[rr][cc] = fmaf(wr[rr].y, w2v[cc].y, t2a[rr][cc]);
                    t2a[rr][cc] = fmaf(wr[rr].z, w2v[cc].z, t2a[rr][cc]);
                    t2a[rr][cc] = fmaf(wr[rr].w, w2v[cc].w, t2a[rr][cc]);
                }
        }
        #pragma unroll
        for (int rr = 0; rr < 2; ++rr)
            #pragma unroll
            for (int cc = 0; cc < 2; ++cc) {
                int row = r0 + rr, j = c0 + cc;
                float s  = sb[row][j];
                float sg = (j < NSIGN) ? -1.f : 1.f;
                float cv = sg * s * (1.f - s);
                float g  = sg * (s + CCONST);
                float gi = 1.f / g;
                float vvl = xv[row][DIM + j];
                float dv = fmaf(-gi, t1a[rr][cc], 2.f * vvl * gi * cv * t2a[rr][cc]);
                out[(size_t)(b0 + row) * DIM2 + DIM + j] = dv;
            }
    }
}

extern "C" void kernel_launch(void* const* d_in, const int* in_sizes, int n_in,
                              void* d_out, int out_size, void* d_ws, size_t ws_size,
                              hipStream_t stream) {
    // inputs: t, input_, W1, b1, W2, b2
    const float* input_ = (const float*)d_in[1];
    const float* W1 = (const float*)d_in[2];
    const float* b1 = (const float*)d_in[3];
    const float* W2 = (const float*)d_in[4];
    const float* b2 = (const float*)d_in[5];
    float* out = (float*)d_out;

    float* W1T = (float*)d_ws;            // 128*256 floats
    float* W2T = W1T + DIM * DIM2;        // 256*128 floats

    const int batch = in_sizes[1] / DIM2;

    prep_transpose<<<(DIM * DIM2 + 255) / 256, 256, 0, stream>>>(W1, W2, W1T, W2T);
    fused_connection<<<batch / TB, NTHR, 0, stream>>>(input_, W1, b1, W2, b2, W1T, W2T, out);
}

// Round 2
// 76.772 us; speedup vs baseline: 2.2608x; 2.2608x over previous
//
#include <hip/hip_runtime.h>
#include <math.h>

#define DIM    128
#define DIM2   256
#define NSIGN  4
#define CCONST 0.618f
#define TB     8
#define NTHR   256

// Build W1T[j][k] = W1[k][j]  (W1 is [256][128])
//       W2T[k][i] = W2[i][k]  (W2 is [128][256])
__global__ void prep_transpose(const float* __restrict__ W1,
                               const float* __restrict__ W2,
                               float* __restrict__ W1T,
                               float* __restrict__ W2T) {
    int idx = blockIdx.x * blockDim.x + threadIdx.x;
    if (idx >= DIM * DIM2) return;
    int k = idx >> 7;            // W1 row (0..255)
    int j = idx & (DIM - 1);     // W1 col (0..127)
    W1T[j * DIM2 + k] = W1[idx];
    int i  = idx >> 8;           // W2 row (0..127)
    int kk = idx & (DIM2 - 1);   // W2 col (0..255)
    W2T[kk * DIM + i] = W2[idx];
}

__global__ __launch_bounds__(NTHR, 2)
void fused_connection(const float* __restrict__ input_,
                      const float* __restrict__ W1,
                      const float* __restrict__ b1,
                      const float* __restrict__ W2,
                      const float* __restrict__ b2,
                      const float* __restrict__ W1T,
                      const float* __restrict__ W2T,
                      float* __restrict__ out) {
    // Per-block LDS: 32 KB
    __shared__ __align__(16) float xv[TB][DIM2]; // x | v ; x-half becomes vc after stage 2
    __shared__ __align__(16) float am[TB][DIM2]; // a = relu(h)  (mask source)
    __shared__ __align__(16) float wb[TB][DIM2]; // w = v@W1^T; masked in stage 3
    __shared__ __align__(16) float ub[TB][DIM2]; // mu = mask * u

    const int t  = threadIdx.x;
    const int b0 = blockIdx.x * TB;

    // ---------- Phase 0: load x|v rows (TB*256 floats, coalesced float4) ----------
    {
        const float4* src = (const float4*)(input_ + (size_t)b0 * DIM2);
        float4* dst = (float4*)(&xv[0][0]);
        dst[t]        = src[t];
        dst[t + NTHR] = src[t + NTHR];
    }
    __syncthreads();

    // copy v -> out[:, :128]
    {
        int row  = t >> 5;
        int col4 = (t & 31) * 4;
        float4 vv = *(const float4*)(&xv[row][DIM + col4]);
        *(float4*)(out + (size_t)(b0 + row) * DIM2 + col4) = vv;
    }

    // Mappings:
    //   N=256 stages (1,3): rg = t>>7 (2 groups x 4 rows), k0 = (t&127)*2 (2 cols)
    //   N=128 stages (2,4): rg2 = t>>6 (4 groups x 2 rows), i0 = (t&63)*2 (2 cols)
    const int rg  = t >> 7;
    const int r0  = rg * 4;
    const int k0  = (t & 127) * 2;
    const int rg2 = t >> 6;
    const int r2  = rg2 * 2;
    const int i0  = (t & 63) * 2;

    // ---------- Stage 1: h[b,k] = x.W1[k,:] + b1[k]; w[b,k] = v.W1[k,:] ----------
    // weights from W1T[j][k] -> lanes contiguous in k. 4 rows x 2 cols per thread.
    {
        float ha[4][2], wa[4][2];
        const float bv0 = b1[k0], bv1 = b1[k0 + 1];
        #pragma unroll
        for (int rr = 0; rr < 4; ++rr) {
            ha[rr][0] = bv0; ha[rr][1] = bv1;
            wa[rr][0] = 0.f; wa[rr][1] = 0.f;
        }
        #pragma unroll 4
        for (int j4 = 0; j4 < DIM; j4 += 4) {
            const float2 w0 = *(const float2*)(W1T + (j4 + 0) * DIM2 + k0);
            const float2 w1 = *(const float2*)(W1T + (j4 + 1) * DIM2 + k0);
            const float2 w2 = *(const float2*)(W1T + (j4 + 2) * DIM2 + k0);
            const float2 w3 = *(const float2*)(W1T + (j4 + 3) * DIM2 + k0);
            #pragma unroll
            for (int rr = 0; rr < 4; ++rr) {
                const float4 xr = *(const float4*)(&xv[r0 + rr][j4]);
                const float4 vr = *(const float4*)(&xv[r0 + rr][DIM + j4]);
                ha[rr][0] = fmaf(xr.x, w0.x, ha[rr][0]); ha[rr][1] = fmaf(xr.x, w0.y, ha[rr][1]);
                ha[rr][0] = fmaf(xr.y, w1.x, ha[rr][0]); ha[rr][1] = fmaf(xr.y, w1.y, ha[rr][1]);
                ha[rr][0] = fmaf(xr.z, w2.x, ha[rr][0]); ha[rr][1] = fmaf(xr.z, w2.y, ha[rr][1]);
                ha[rr][0] = fmaf(xr.w, w3.x, ha[rr][0]); ha[rr][1] = fmaf(xr.w, w3.y, ha[rr][1]);
                wa[rr][0] = fmaf(vr.x, w0.x, wa[rr][0]); wa[rr][1] = fmaf(vr.x, w0.y, wa[rr][1]);
                wa[rr][0] = fmaf(vr.y, w1.x, wa[rr][0]); wa[rr][1] = fmaf(vr.y, w1.y, wa[rr][1]);
                wa[rr][0] = fmaf(vr.z, w2.x, wa[rr][0]); wa[rr][1] = fmaf(vr.z, w2.y, wa[rr][1]);
                wa[rr][0] = fmaf(vr.w, w3.x, wa[rr][0]); wa[rr][1] = fmaf(vr.w, w3.y, wa[rr][1]);
            }
        }
        #pragma unroll
        for (int rr = 0; rr < 4; ++rr) {
            float2 av, wv;
            av.x = fmaxf(ha[rr][0], 0.f); av.y = fmaxf(ha[rr][1], 0.f);
            wv.x = wa[rr][0];             wv.y = wa[rr][1];
            *(float2*)(&am[r0 + rr][k0]) = av;
            *(float2*)(&wb[r0 + rr][k0]) = wv;
        }
    }
    __syncthreads();

    // ---------- Stage 2: z[b,i] = a.W2[i,:] + b2[i]; s kept in regs; vc -> xv x-half ----------
    // weights from W2T[k][i] -> lanes contiguous in i. 2 rows x 2 cols per thread.
    float sreg[2][2];
    {
        float za[2][2];
        const float bz0 = b2[i0], bz1 = b2[i0 + 1];
        za[0][0] = bz0; za[0][1] = bz1; za[1][0] = bz0; za[1][1] = bz1;
        #pragma unroll 4
        for (int k4 = 0; k4 < DIM2; k4 += 4) {
            const float2 q0 = *(const float2*)(W2T + (k4 + 0) * DIM + i0);
            const float2 q1 = *(const float2*)(W2T + (k4 + 1) * DIM + i0);
            const float2 q2 = *(const float2*)(W2T + (k4 + 2) * DIM + i0);
            const float2 q3 = *(const float2*)(W2T + (k4 + 3) * DIM + i0);
            #pragma unroll
            for (int rr = 0; rr < 2; ++rr) {
                const float4 ar = *(const float4*)(&am[r2 + rr][k4]);
                za[rr][0] = fmaf(ar.x, q0.x, za[rr][0]); za[rr][1] = fmaf(ar.x, q0.y, za[rr][1]);
                za[rr][0] = fmaf(ar.y, q1.x, za[rr][0]); za[rr][1] = fmaf(ar.y, q1.y, za[rr][1]);
                za[rr][0] = fmaf(ar.z, q2.x, za[rr][0]); za[rr][1] = fmaf(ar.z, q2.y, za[rr][1]);
                za[rr][0] = fmaf(ar.w, q3.x, za[rr][0]); za[rr][1] = fmaf(ar.w, q3.y, za[rr][1]);
            }
        }
        const float sg0 = (i0     < NSIGN) ? -1.f : 1.f;
        const float sg1 = (i0 + 1 < NSIGN) ? -1.f : 1.f;
        #pragma unroll
        for (int rr = 0; rr < 2; ++rr) {
            const int row = r2 + rr;
            const float s0 = 1.f / (1.f + __expf(-za[rr][0]));
            const float s1 = 1.f / (1.f + __expf(-za[rr][1]));
            sreg[rr][0] = s0; sreg[rr][1] = s1;
            const float2 vv = *(const float2*)(&xv[row][DIM + i0]);
            float2 vc;
            vc.x = vv.x * vv.x * sg0 * s0 * (1.f - s0);
            vc.y = vv.y * vv.y * sg1 * s1 * (1.f - s1);
            *(float2*)(&xv[row][i0]) = vc;   // overwrite dead x-half
        }
    }
    __syncthreads();

    // ---------- Stage 3: u[b,k] = vc.W2[:,k]; mu = m*u -> ub; mw = m*w -> wb ----------
    // weights from W2[i][k] (native row-major) -> lanes contiguous in k. 4 rows x 2 cols.
    {
        float ua[4][2] = {{0.f,0.f},{0.f,0.f},{0.f,0.f},{0.f,0.f}};
        #pragma unroll 4
        for (int i4 = 0; i4 < DIM; i4 += 4) {
            const float2 w0 = *(const float2*)(W2 + (i4 + 0) * DIM2 + k0);
            const float2 w1 = *(const float2*)(W2 + (i4 + 1) * DIM2 + k0);
            const float2 w2 = *(const float2*)(W2 + (i4 + 2) * DIM2 + k0);
            const float2 w3 = *(const float2*)(W2 + (i4 + 3) * DIM2 + k0);
            #pragma unroll
            for (int rr = 0; rr < 4; ++rr) {
                const float4 cr = *(const float4*)(&xv[r0 + rr][i4]);
                ua[rr][0] = fmaf(cr.x, w0.x, ua[rr][0]); ua[rr][1] = fmaf(cr.x, w0.y, ua[rr][1]);
                ua[rr][0] = fmaf(cr.y, w1.x, ua[rr][0]); ua[rr][1] = fmaf(cr.y, w1.y, ua[rr][1]);
                ua[rr][0] = fmaf(cr.z, w2.x, ua[rr][0]); ua[rr][1] = fmaf(cr.z, w2.y, ua[rr][1]);
                ua[rr][0] = fmaf(cr.w, w3.x, ua[rr][0]); ua[rr][1] = fmaf(cr.w, w3.y, ua[rr][1]);
            }
        }
        #pragma unroll
        for (int rr = 0; rr < 4; ++rr) {
            const int row = r0 + rr;
            const float2 amv = *(const float2*)(&am[row][k0]);
            const float2 wv  = *(const float2*)(&wb[row][k0]);
            float2 uo, wo;
            uo.x = (amv.x > 0.f) ? ua[rr][0] : 0.f;  wo.x = (amv.x > 0.f) ? wv.x : 0.f;
            uo.y = (amv.y > 0.f) ? ua[rr][1] : 0.f;  wo.y = (amv.y > 0.f) ? wv.y : 0.f;
            *(float2*)(&ub[row][k0]) = uo;
            *(float2*)(&wb[row][k0]) = wo;
        }
    }
    __syncthreads();

    // ---------- Stage 4: t1[b,j] = mu.W1[:,j]; t2[b,j] = mw.W2T[:,j]; dv ----------
    // W1[k][j] native (j contiguous), W2T[k][j] (j contiguous). 2 rows x 2 cols.
    {
        float t1a[2][2] = {{0.f,0.f},{0.f,0.f}};
        float t2a[2][2] = {{0.f,0.f},{0.f,0.f}};
        #pragma unroll 4
        for (int k4 = 0; k4 < DIM2; k4 += 4) {
            const float2 a0 = *(const float2*)(W1  + (k4 + 0) * DIM + i0);
            const float2 a1 = *(const float2*)(W1  + (k4 + 1) * DIM + i0);
            const float2 a2 = *(const float2*)(W1  + (k4 + 2) * DIM + i0);
            const float2 a3 = *(const float2*)(W1  + (k4 + 3) * DIM + i0);
            const float2 c0 = *(const float2*)(W2T + (k4 + 0) * DIM + i0);
            const float2 c1 = *(const float2*)(W2T + (k4 + 1) * DIM + i0);
            const float2 c2 = *(const float2*)(W2T + (k4 + 2) * DIM + i0);
            const float2 c3 = *(const float2*)(W2T + (k4 + 3) * DIM + i0);
            #pragma unroll
            for (int rr = 0; rr < 2; ++rr) {
                const float4 ur = *(const float4*)(&ub[r2 + rr][k4]);
                const float4 wr = *(const float4*)(&wb[r2 + rr][k4]);
                t1a[rr][0] = fmaf(ur.x, a0.x, t1a[rr][0]); t1a[rr][1] = fmaf(ur.x, a0.y, t1a[rr][1]);
                t1a[rr][0] = fmaf(ur.y, a1.x, t1a[rr][0]); t1a[rr][1] = fmaf(ur.y, a1.y, t1a[rr][1]);
                t1a[rr][0] = fmaf(ur.z, a2.x, t1a[rr][0]); t1a[rr][1] = fmaf(ur.z, a2.y, t1a[rr][1]);
                t1a[rr][0] = fmaf(ur.w, a3.x, t1a[rr][0]); t1a[rr][1] = fmaf(ur.w, a3.y, t1a[rr][1]);
                t2a[rr][0] = fmaf(wr.x, c0.x, t2a[rr][0]); t2a[rr][1] = fmaf(wr.x, c0.y, t2a[rr][1]);
                t2a[rr][0] = fmaf(wr.y, c1.x, t2a[rr][0]); t2a[rr][1] = fmaf(wr.y, c1.y, t2a[rr][1]);
                t2a[rr][0] = fmaf(wr.z, c2.x, t2a[rr][0]); t2a[rr][1] = fmaf(wr.z, c2.y, t2a[rr][1]);
                t2a[rr][0] = fmaf(wr.w, c3.x, t2a[rr][0]); t2a[rr][1] = fmaf(wr.w, c3.y, t2a[rr][1]);
            }
        }
        const float sg0 = (i0     < NSIGN) ? -1.f : 1.f;
        const float sg1 = (i0 + 1 < NSIGN) ? -1.f : 1.f;
        #pragma unroll
        for (int rr = 0; rr < 2; ++rr) {
            const int row = r2 + rr;
            const float s0 = sreg[rr][0], s1 = sreg[rr][1];
            const float cv0 = sg0 * s0 * (1.f - s0);
            const float cv1 = sg1 * s1 * (1.f - s1);
            const float gi0 = 1.f / (sg0 * (s0 + CCONST));
            const float gi1 = 1.f / (sg1 * (s1 + CCONST));
            const float2 vv = *(const float2*)(&xv[row][DIM + i0]);
            float2 dvp;
            dvp.x = fmaf(-gi0, t1a[rr][0], 2.f * vv.x * gi0 * cv0 * t2a[rr][0]);
            dvp.y = fmaf(-gi1, t1a[rr][1], 2.f * vv.y * gi1 * cv1 * t2a[rr][1]);
            *(float2*)(out + (size_t)(b0 + row) * DIM2 + DIM + i0) = dvp;
        }
    }
}

extern "C" void kernel_launch(void* const* d_in, const int* in_sizes, int n_in,
                              void* d_out, int out_size, void* d_ws, size_t ws_size,
                              hipStream_t stream) {
    // inputs: t, input_, W1, b1, W2, b2
    const float* input_ = (const float*)d_in[1];
    const float* W1 = (const float*)d_in[2];
    const float* b1 = (const float*)d_in[3];
    const float* W2 = (const float*)d_in[4];
    const float* b2 = (const float*)d_in[5];
    float* out = (float*)d_out;

    float* W1T = (float*)d_ws;            // 128*256 floats
    float* W2T = W1T + DIM * DIM2;        // 256*128 floats

    const int batch = in_sizes[1] / DIM2;

    prep_transpose<<<(DIM * DIM2 + 255) / 256, 256, 0, stream>>>(W1, W2, W1T, W2T);
    fused_connection<<<batch / TB, NTHR, 0, stream>>>(input_, W1, b1, W2, b2, W1T, W2T, out);
}